// Round 1
// baseline (1073.338 us; speedup 1.0000x reference)
//
#include <hip/hip_runtime.h>
#include <hip/hip_cooperative_groups.h>
#include <stdint.h>

namespace cg = cooperative_groups;

#define NB 32
#define NN 524288
#define NPTS 16384
#define NSEG 8             // padded sub-counters per batch for block appends
#define SEGCAP 4096        // slots per segment (E~2196/seg, sd~47)
#define SCAP 20480         // scatter buffer per batch (>= 16384 + max bin)
#define NBINS 4096
#define THRESH 0.0478515625f   // 3136/65536 exact; u_(16384)~0.0448, 9-sigma
#define CNTSTRIDE 32       // uint32s per counter -> 128B line padding
#define GRID 1024          // cooperative: 4 blocks/CU x 256 CUs
#define BLK 256
#define NTHR (GRID * BLK)  // 262144 threads

struct Keys { uint32_t k[2 * NB]; };

__host__ __device__ static inline void tf2x32(uint32_t k0, uint32_t k1,
                                              uint32_t x0, uint32_t x1,
                                              uint32_t* o0, uint32_t* o1) {
  uint32_t ks2 = k0 ^ k1 ^ 0x1BD11BDAu;
  x0 += k0; x1 += k1;
#define TFR(r) { x0 += x1; x1 = (x1 << (r)) | (x1 >> (32 - (r))); x1 ^= x0; }
  TFR(13) TFR(15) TFR(26) TFR(6)
  x0 += k1; x1 += ks2 + 1u;
  TFR(17) TFR(29) TFR(16) TFR(24)
  x0 += ks2; x1 += k0 + 2u;
  TFR(13) TFR(15) TFR(26) TFR(6)
  x0 += k0; x1 += k1 + 3u;
  TFR(17) TFR(29) TFR(16) TFR(24)
  x0 += k1; x1 += ks2 + 4u;
  TFR(13) TFR(15) TFR(26) TFR(6)
  x0 += ks2; x1 += k0 + 5u;
#undef TFR
  *o0 = x0; *o1 = x1;
}

// ---------------- Fused cooperative pipeline ----------------
// P0 zero counters -> P1 candidates+hist -> P2 scan -> P3 scatter -> P4 rank.
// Each phase boundary: __threadfence() (device-scope, cross-XCD L2) + grid.sync().
__global__ __launch_bounds__(BLK, 4) void k_fused(
    const float* __restrict__ p, Keys keys,
    uint64_t* __restrict__ cand, uint32_t* __restrict__ cand_cnt,
    uint32_t* __restrict__ hist, uint32_t* __restrict__ cum,
    uint32_t* __restrict__ scount, uint32_t* __restrict__ fill,
    uint64_t* __restrict__ sorted, float* __restrict__ out) {
  cg::grid_group gg = cg::this_grid();
  const int t = threadIdx.x;
  const int gtid = blockIdx.x * BLK + t;
  __shared__ uint32_t lcnt, lbase;
  __shared__ uint32_t wsum[4];

  // ---- P0: zero cnt(32KB)+hist(512KB)+fill(512KB), contiguous ----
  {
    uint4* zb = (uint4*)cand_cnt;
    const int nz = (NB * NSEG * CNTSTRIDE + 2 * NB * NBINS) / 4;  // 67584
    const uint4 z = make_uint4(0u, 0u, 0u, 0u);
    for (int i = gtid; i < nz; i += NTHR) zb[i] = z;
  }
  __threadfence();
  gg.sync();

  // ---- P1: mask + threefry + hist count + LDS-compacted append ----
  for (int tile = blockIdx.x; tile < NB * (NN / 1024); tile += GRID) {
    const int b = tile >> 9;                 // 512 tiles per batch
    const int ch = tile & 511;
    const int i0 = (ch * BLK + t) * 4;       // first of 4 points
    const uint32_t kp0 = keys.k[2 * b], kp1 = keys.k[2 * b + 1];
    const float4* p4 = (const float4*)(p + (size_t)b * NN * 3) +
                       (size_t)(ch * BLK + t) * 3;
    float4 v0 = p4[0], v1 = p4[1], v2 = p4[2];
    float px[4] = {v0.x, v0.w, v1.z, v2.y};
    float py[4] = {v0.y, v1.x, v1.w, v2.z};
    float pz[4] = {v0.z, v1.y, v2.x, v2.w};
    uint32_t* hb = hist + (size_t)b * NBINS;
    uint64_t mykeys[4];
    int nc = 0;
#pragma unroll
    for (int j = 0; j < 4; ++j) {
      uint32_t o0, o1;
      tf2x32(kp0, kp1, 0u, (uint32_t)(i0 + j), &o0, &o1);
      uint32_t bits = o0 ^ o1;
      float u = __uint_as_float((bits >> 9) | 0x3F800000u) - 1.0f;
      float s = (px[j] + py[j]) + pz[j];
      if ((s != 0.0f) && (u < THRESH)) {
        mykeys[nc++] = ((uint64_t)__float_as_uint(u) << 32) | (uint32_t)(i0 + j);
        atomicAdd(&hb[(int)(u * 65536.0f)], 1u);
      }
    }
    if (t == 0) lcnt = 0u;
    __syncthreads();
    uint32_t loc = 0u;
    if (nc) loc = atomicAdd(&lcnt, (uint32_t)nc);
    __syncthreads();
    const int seg = ch & (NSEG - 1);
    if (t == 0) lbase = atomicAdd(&cand_cnt[(b * NSEG + seg) * CNTSTRIDE], lcnt);
    __syncthreads();
    uint64_t* cb = cand + ((size_t)b * NSEG + seg) * SEGCAP;
    for (int j = 0; j < nc; ++j) {
      uint32_t slot = lbase + loc + j;
      if (slot < SEGCAP) cb[slot] = mykeys[j];
    }
    // no trailing sync needed: next tile's lbase write is after its 2nd sync
  }
  __threadfence();
  gg.sync();

  // ---- P2: per-batch exclusive scan of 4096 bins (blocks 0..31) ----
  if (blockIdx.x < NB) {
    const int b = blockIdx.x;
    const int lane = t & 63, wave = t >> 6;
    const uint4* hb4 = (const uint4*)(hist + (size_t)b * NBINS);
    uint4 ha = hb4[4 * t], hbv = hb4[4 * t + 1],
          hc = hb4[4 * t + 2], hd = hb4[4 * t + 3];
    uint32_t h[16] = {ha.x, ha.y, ha.z, ha.w, hbv.x, hbv.y, hbv.z, hbv.w,
                      hc.x, hc.y, hc.z, hc.w, hd.x, hd.y, hd.z, hd.w};
    uint32_t s = 0;
#pragma unroll
    for (int q = 0; q < 16; ++q) s += h[q];
    uint32_t v = s;
    for (int off = 1; off < 64; off <<= 1) {
      uint32_t n = __shfl_up(v, off, 64);
      if (lane >= off) v += n;
    }
    if (lane == 63) wsum[wave] = v;
    __syncthreads();
    uint32_t woff = 0;
#pragma unroll
    for (int w = 0; w < 3; ++w) if (wave > w) woff += wsum[w];
    const uint32_t incl = v + woff;
    uint32_t c[17];
    c[0] = incl - s;
#pragma unroll
    for (int q = 0; q < 16; ++q) c[q + 1] = c[q] + h[q];
    uint32_t* gc = cum + (size_t)b * (NBINS + 1);
#pragma unroll
    for (int q = 0; q < 16; ++q) gc[16 * t + q] = c[q];
    if (t == BLK - 1) gc[NBINS] = incl;
#pragma unroll
    for (int q = 0; q < 16; ++q)
      if (c[q] < NPTS && c[q + 1] >= NPTS) {
        uint32_t sc = c[q + 1];
        scount[b] = (sc > SCAP) ? SCAP : sc;
      }
    if (t == BLK - 1 && incl < NPTS) scount[b] = incl;   // defensive
  }
  __threadfence();
  gg.sync();

  // ---- P3: thread-per-candidate scatter into bin-contiguous slots ----
  for (int idx = gtid; idx < NB * NSEG * SEGCAP; idx += NTHR) {
    const int b = idx >> 15;                 // 32768 slots per batch
    const int j = idx & 32767;
    const int sg = j >> 12;
    const int jj = j & (SEGCAP - 1);
    uint32_t M = cand_cnt[(b * NSEG + sg) * CNTSTRIDE];
    if (M > SEGCAP) M = SEGCAP;
    if ((uint32_t)jj < M) {
      uint64_t key = cand[((size_t)b * NSEG + sg) * SEGCAP + jj];
      float u = __uint_as_float((uint32_t)(key >> 32));
      int bin = (int)(u * 65536.0f);
      uint32_t c0 = cum[(size_t)b * (NBINS + 1) + bin];
      if (c0 < NPTS) {
        uint32_t pos = atomicAdd(&fill[(size_t)b * NBINS + bin], 1u);
        uint32_t sl = c0 + pos;
        if (sl < SCAP) sorted[(size_t)b * SCAP + sl] = key;
      }
    }
  }
  __threadfence();
  gg.sync();

  // ---- P4: exact rank within bin + gather + emit ----
  for (int idx = gtid; idx < NB * SCAP; idx += NTHR) {
    const int b = idx / SCAP;
    const uint32_t j = (uint32_t)(idx - b * SCAP);
    if (j >= scount[b]) continue;
    const uint64_t* sb = sorted + (size_t)b * SCAP;
    uint64_t key = sb[j];
    float u = __uint_as_float((uint32_t)(key >> 32));
    int bin = (int)(u * 65536.0f);
    const uint32_t* gc = cum + (size_t)b * (NBINS + 1);
    uint32_t c0 = gc[bin], c1 = gc[bin + 1];
    uint32_t r = c0;
    for (uint32_t l = c0; l < c1; ++l) r += (sb[l] < key) ? 1u : 0u;
    if (r < NPTS) {
      uint32_t pidx = (uint32_t)key;
      const float* pp = p + (size_t)b * NN * 3 + 3 * (size_t)pidx;
      float* o = out + ((size_t)b * NPTS + r) * 3;
      o[0] = pp[0]; o[1] = pp[1]; o[2] = pp[2];
    }
  }
}

// ---------------- Legacy 4-kernel path (fallback only) ----------------
__global__ __launch_bounds__(256) void k_candidates(
    const float* __restrict__ p, Keys keys,
    uint64_t* __restrict__ cand, uint32_t* __restrict__ cand_cnt,
    uint32_t* __restrict__ hist) {
  const int b = blockIdx.y;
  const int t = threadIdx.x;
  const int i0 = (blockIdx.x * 256 + t) * 4;
  const uint32_t kp0 = keys.k[2 * b], kp1 = keys.k[2 * b + 1];
  const float4* p4 = (const float4*)(p + (size_t)b * NN * 3) +
                     (size_t)(blockIdx.x * 256 + t) * 3;
  float4 v0 = p4[0], v1 = p4[1], v2 = p4[2];
  float px[4] = {v0.x, v0.w, v1.z, v2.y};
  float py[4] = {v0.y, v1.x, v1.w, v2.z};
  float pz[4] = {v0.z, v1.y, v2.x, v2.w};
  uint32_t* hb = hist + (size_t)b * NBINS;
  uint64_t mykeys[4];
  int nc = 0;
#pragma unroll
  for (int j = 0; j < 4; ++j) {
    uint32_t o0, o1;
    tf2x32(kp0, kp1, 0u, (uint32_t)(i0 + j), &o0, &o1);
    uint32_t bits = o0 ^ o1;
    float u = __uint_as_float((bits >> 9) | 0x3F800000u) - 1.0f;
    float s = (px[j] + py[j]) + pz[j];
    if ((s != 0.0f) && (u < THRESH)) {
      mykeys[nc++] = ((uint64_t)__float_as_uint(u) << 32) | (uint32_t)(i0 + j);
      atomicAdd(&hb[(int)(u * 65536.0f)], 1u);
    }
  }
  __shared__ uint32_t lcnt, lbase;
  if (t == 0) lcnt = 0u;
  __syncthreads();
  uint32_t loc = 0u;
  if (nc) loc = atomicAdd(&lcnt, (uint32_t)nc);
  __syncthreads();
  const int seg = blockIdx.x & (NSEG - 1);
  if (t == 0)
    lbase = atomicAdd(&cand_cnt[(b * NSEG + seg) * CNTSTRIDE], lcnt);
  __syncthreads();
  uint64_t* cb = cand + ((size_t)b * NSEG + seg) * SEGCAP;
  for (int j = 0; j < nc; ++j) {
    uint32_t slot = lbase + loc + j;
    if (slot < SEGCAP) cb[slot] = mykeys[j];
  }
}

__global__ __launch_bounds__(1024) void k_scan(
    const uint32_t* __restrict__ hist, uint32_t* __restrict__ cum,
    uint32_t* __restrict__ scount) {
  const int b = blockIdx.x;
  const int t = threadIdx.x;
  const int lane = t & 63, wave = t >> 6;
  const uint32_t* hb = hist + (size_t)b * NBINS;
  uint32_t h0 = hb[4 * t], h1 = hb[4 * t + 1],
           h2 = hb[4 * t + 2], h3 = hb[4 * t + 3];
  uint32_t s = h0 + h1 + h2 + h3;
  uint32_t v = s;
  for (int off = 1; off < 64; off <<= 1) {
    uint32_t n = __shfl_up(v, off, 64);
    if (lane >= off) v += n;
  }
  __shared__ uint32_t wsum[16];
  if (lane == 63) wsum[wave] = v;
  __syncthreads();
  if (t < 16) {
    uint32_t w = wsum[t];
    for (int off = 1; off < 16; off <<= 1) {
      uint32_t n = __shfl_up(w, off, 64);
      if (t >= off) w += n;
    }
    wsum[t] = w;
  }
  __syncthreads();
  uint32_t incl = v + (wave ? wsum[wave - 1] : 0u);
  uint32_t c[5];
  c[0] = incl - s; c[1] = c[0] + h0; c[2] = c[1] + h1;
  c[3] = c[2] + h2; c[4] = incl;
  uint32_t* gc = cum + (size_t)b * (NBINS + 1);
  gc[4 * t] = c[0]; gc[4 * t + 1] = c[1];
  gc[4 * t + 2] = c[2]; gc[4 * t + 3] = c[3];
  if (t == 1023) gc[NBINS] = incl;
#pragma unroll
  for (int q = 0; q < 4; ++q)
    if (c[q] < NPTS && c[q + 1] >= NPTS) {
      uint32_t sc = c[q + 1];
      scount[b] = (sc > SCAP) ? SCAP : sc;
    }
  if (t == 1023 && incl < NPTS) scount[b] = incl;
}

__global__ __launch_bounds__(256) void k_scatter(
    const uint64_t* __restrict__ cand, const uint32_t* __restrict__ cand_cnt,
    const uint32_t* __restrict__ cum, uint32_t* __restrict__ fill,
    uint64_t* __restrict__ sorted) {
  const int b = blockIdx.y;
  const int j = blockIdx.x * 256 + threadIdx.x;
  const int s = j >> 12;
  const int jj = j & (SEGCAP - 1);
  uint32_t M = cand_cnt[(b * NSEG + s) * CNTSTRIDE];
  if (M > SEGCAP) M = SEGCAP;
  if ((uint32_t)jj >= M) return;
  uint64_t key = cand[((size_t)b * NSEG + s) * SEGCAP + jj];
  float u = __uint_as_float((uint32_t)(key >> 32));
  int bin = (int)(u * 65536.0f);
  uint32_t c0 = cum[(size_t)b * (NBINS + 1) + bin];
  if (c0 >= NPTS) return;
  uint32_t pos = atomicAdd(&fill[(size_t)b * NBINS + bin], 1u);
  uint32_t sl = c0 + pos;
  if (sl < SCAP) sorted[(size_t)b * SCAP + sl] = key;
}

__global__ __launch_bounds__(256) void k_rank(
    const float* __restrict__ p, const uint64_t* __restrict__ sorted,
    const uint32_t* __restrict__ cum, const uint32_t* __restrict__ scount,
    float* __restrict__ out) {
  const int b = blockIdx.y;
  const uint32_t j = blockIdx.x * 256 + threadIdx.x;
  if (j >= scount[b]) return;
  const uint64_t* sb = sorted + (size_t)b * SCAP;
  uint64_t key = sb[j];
  float u = __uint_as_float((uint32_t)(key >> 32));
  int bin = (int)(u * 65536.0f);
  const uint32_t* gc = cum + (size_t)b * (NBINS + 1);
  uint32_t c0 = gc[bin], c1 = gc[bin + 1];
  uint32_t r = c0;
  for (uint32_t l = c0; l < c1; ++l) r += (sb[l] < key) ? 1u : 0u;
  if (r < NPTS) {
    uint32_t idx = (uint32_t)key;
    const float* pp = p + (size_t)b * NN * 3 + 3 * (size_t)idx;
    float* o = out + ((size_t)b * NPTS + r) * 3;
    o[0] = pp[0]; o[1] = pp[1]; o[2] = pp[2];
  }
}

extern "C" void kernel_launch(void* const* d_in, const int* in_sizes, int n_in,
                              void* d_out, int out_size, void* d_ws, size_t ws_size,
                              hipStream_t stream) {
  const float* p = (const float*)d_in[0];
  float* out = (float*)d_out;
  uint8_t* ws = (uint8_t*)d_ws;

  size_t off_cand   = 0;                                            // 8 MB
  size_t off_sorted = off_cand + (size_t)NB * NSEG * SEGCAP * 8;    // +5.24 MB
  size_t off_cum    = off_sorted + (size_t)NB * SCAP * 8;           // +0.52 MB
  size_t off_scnt   = off_cum + (size_t)NB * (NBINS + 1) * 4;       // +128 B
  size_t off_zero   = off_scnt + 128;                               // zeroed:
  size_t off_cnt    = off_zero;                                     //  cnt 32 KB
  size_t off_hist   = off_cnt + (size_t)NB * NSEG * CNTSTRIDE * 4;  //  hist 512 KB
  size_t off_fill   = off_hist + (size_t)NB * NBINS * 4;            //  fill 512 KB
  size_t zero_bytes = off_fill + (size_t)NB * NBINS * 4 - off_zero;

  uint64_t* cand     = (uint64_t*)(ws + off_cand);
  uint64_t* sorted   = (uint64_t*)(ws + off_sorted);
  uint32_t* cum      = (uint32_t*)(ws + off_cum);
  uint32_t* scount   = (uint32_t*)(ws + off_scnt);
  uint32_t* cand_cnt = (uint32_t*)(ws + off_cnt);
  uint32_t* hist     = (uint32_t*)(ws + off_hist);
  uint32_t* fill     = (uint32_t*)(ws + off_fill);

  // Host-side threefry key derivation (verified absmax=0):
  Keys keys;
  for (int b = 0; b < NB; ++b) {
    uint32_t kb0, kb1, kp0, kp1;
    tf2x32(0u, 42u, 0u, (uint32_t)b, &kb0, &kb1);
    tf2x32(kb0, kb1, 0u, 0u, &kp0, &kp1);
    keys.k[2 * b] = kp0; keys.k[2 * b + 1] = kp1;
  }

  // Single cooperative dispatch: zero + candidates + scan + scatter + rank.
  void* args[10];
  args[0] = (void*)&p;       args[1] = (void*)&keys;
  args[2] = (void*)&cand;    args[3] = (void*)&cand_cnt;
  args[4] = (void*)&hist;    args[5] = (void*)&cum;
  args[6] = (void*)&scount;  args[7] = (void*)&fill;
  args[8] = (void*)&sorted;  args[9] = (void*)&out;
  hipError_t err = hipLaunchCooperativeKernel((const void*)k_fused,
                                              dim3(GRID), dim3(BLK),
                                              args, 0, stream);
  if (err != hipSuccess) {
    // Fallback: proven 5-dispatch pipeline (baseline semantics).
    hipMemsetAsync(ws + off_zero, 0, zero_bytes, stream);
    dim3 g1(NN / 1024, NB);
    k_candidates<<<g1, 256, 0, stream>>>(p, keys, cand, cand_cnt, hist);
    k_scan<<<NB, 1024, 0, stream>>>(hist, cum, scount);
    dim3 g3(NSEG * SEGCAP / 256, NB);
    k_scatter<<<g3, 256, 0, stream>>>(cand, cand_cnt, cum, fill, sorted);
    dim3 g4(SCAP / 256, NB);
    k_rank<<<g4, 256, 0, stream>>>(p, sorted, cum, scount, out);
  }
}

// Round 2
// 327.254 us; speedup vs baseline: 3.2798x; 3.2798x over previous
//
#include <hip/hip_runtime.h>
#include <stdint.h>

#define NB 32
#define NN 524288
#define NPTS 16384
#define NSEG 8             // padded sub-counters per batch for K1 block appends
#define SEGCAP 4096        // slots per segment (E=2196, sd~47 at tight THRESH)
#define SCAP 20480         // scatter buffer per batch (>= 16384 + max bin ~30)
#define NBINS 4096
#define THRESH 0.0478515625f   // 3136/65536 exact; u_(16384)~0.0448, 9-sigma
#define CNTSTRIDE 32       // uint32s per counter -> 128B line padding
#define K23T 512           // threads for fused scan+scatter kernel

struct Keys { uint32_t k[2 * NB]; };

__host__ __device__ static inline void tf2x32(uint32_t k0, uint32_t k1,
                                              uint32_t x0, uint32_t x1,
                                              uint32_t* o0, uint32_t* o1) {
  uint32_t ks2 = k0 ^ k1 ^ 0x1BD11BDAu;
  x0 += k0; x1 += k1;
#define TFR(r) { x0 += x1; x1 = (x1 << (r)) | (x1 >> (32 - (r))); x1 ^= x0; }
  TFR(13) TFR(15) TFR(26) TFR(6)
  x0 += k1; x1 += ks2 + 1u;
  TFR(17) TFR(29) TFR(16) TFR(24)
  x0 += ks2; x1 += k0 + 2u;
  TFR(13) TFR(15) TFR(26) TFR(6)
  x0 += k0; x1 += k1 + 3u;
  TFR(17) TFR(29) TFR(16) TFR(24)
  x0 += k1; x1 += ks2 + 4u;
  TFR(13) TFR(15) TFR(26) TFR(6)
  x0 += ks2; x1 += k0 + 5u;
#undef TFR
  *o0 = x0; *o1 = x1;
}

// K1: mask + threefry + fused hist count + LDS-compacted coalesced append.
// (Measured winner: random-bin atomics do NOT live here — one padded
// sub-counter atomic per block, candidates written contiguously.)
__global__ __launch_bounds__(256) void k_candidates(
    const float* __restrict__ p, Keys keys,
    uint64_t* __restrict__ cand, uint32_t* __restrict__ cand_cnt,
    uint32_t* __restrict__ hist) {
  const int b = blockIdx.y;
  const int t = threadIdx.x;
  const int i0 = (blockIdx.x * 256 + t) * 4;            // first of 4 points
  const uint32_t kp0 = keys.k[2 * b], kp1 = keys.k[2 * b + 1];

  const float4* p4 = (const float4*)(p + (size_t)b * NN * 3) +
                     (size_t)(blockIdx.x * 256 + t) * 3;
  float4 v0 = p4[0], v1 = p4[1], v2 = p4[2];
  float px[4] = {v0.x, v0.w, v1.z, v2.y};
  float py[4] = {v0.y, v1.x, v1.w, v2.z};
  float pz[4] = {v0.z, v1.y, v2.x, v2.w};
  uint32_t* hb = hist + (size_t)b * NBINS;
  uint64_t mykeys[4];
  int nc = 0;
#pragma unroll
  for (int j = 0; j < 4; ++j) {
    uint32_t o0, o1;
    tf2x32(kp0, kp1, 0u, (uint32_t)(i0 + j), &o0, &o1);
    uint32_t bits = o0 ^ o1;
    float u = __uint_as_float((bits >> 9) | 0x3F800000u) - 1.0f;
    float s = (px[j] + py[j]) + pz[j];
    if ((s != 0.0f) && (u < THRESH)) {
      mykeys[nc++] = ((uint64_t)__float_as_uint(u) << 32) | (uint32_t)(i0 + j);
      atomicAdd(&hb[(int)(u * 65536.0f)], 1u);    // count only (no return dep)
    }
  }

  __shared__ uint32_t lcnt, lbase;
  if (t == 0) lcnt = 0u;
  __syncthreads();
  uint32_t loc = 0u;
  if (nc) loc = atomicAdd(&lcnt, (uint32_t)nc);
  __syncthreads();
  const int seg = blockIdx.x & (NSEG - 1);
  if (t == 0)
    lbase = atomicAdd(&cand_cnt[(b * NSEG + seg) * CNTSTRIDE], lcnt);
  __syncthreads();
  uint64_t* cb = cand + ((size_t)b * NSEG + seg) * SEGCAP;
  for (int j = 0; j < nc; ++j) {
    uint32_t slot = lbase + loc + j;
    if (slot < SEGCAP) cb[slot] = mykeys[j];
  }
}

// K23: fused scan+scatter. Block = (segment s, batch b). Each block
// redundantly scans its batch's 4096-bin hist into LDS (16 KB from L2,
// ~8 blocks/batch duplicate work is ~2 us total), then scatters its
// segment's candidates through the LDS cum. Segment-0 blocks publish
// cum + scount to global for K4. Removes the separate 32-block scan
// dispatch (latency-bound ~10-15 us).
__global__ __launch_bounds__(K23T) void k_scan_scatter(
    const uint32_t* __restrict__ hist, const uint64_t* __restrict__ cand,
    const uint32_t* __restrict__ cand_cnt, uint32_t* __restrict__ cum,
    uint32_t* __restrict__ scount, uint32_t* __restrict__ fill,
    uint64_t* __restrict__ sorted) {
  const int b = blockIdx.y;
  const int s = blockIdx.x;                 // segment 0..NSEG-1
  const int t = threadIdx.x;                // 0..511
  const int lane = t & 63, wave = t >> 6;
  __shared__ uint32_t lcum[NBINS + 1];
  __shared__ uint32_t wsum[K23T / 64];

  // ---- per-block scan of this batch's hist (8 bins/thread) ----
  const uint4* hb4 = (const uint4*)(hist + (size_t)b * NBINS);
  uint4 ha = hb4[2 * t], hc = hb4[2 * t + 1];
  uint32_t h[8] = {ha.x, ha.y, ha.z, ha.w, hc.x, hc.y, hc.z, hc.w};
  uint32_t ssum = 0;
#pragma unroll
  for (int q = 0; q < 8; ++q) ssum += h[q];
  uint32_t v = ssum;
  for (int off = 1; off < 64; off <<= 1) {
    uint32_t n = __shfl_up(v, off, 64);
    if (lane >= off) v += n;
  }
  if (lane == 63) wsum[wave] = v;
  __syncthreads();
  uint32_t woff = 0;
#pragma unroll
  for (int w = 0; w < K23T / 64 - 1; ++w) if (wave > w) woff += wsum[w];
  const uint32_t incl = v + woff;
  uint32_t c[9];
  c[0] = incl - ssum;
#pragma unroll
  for (int q = 0; q < 8; ++q) c[q + 1] = c[q] + h[q];
#pragma unroll
  for (int q = 0; q < 8; ++q) lcum[8 * t + q] = c[q];
  if (t == K23T - 1) lcum[NBINS] = incl;

  if (s == 0) {   // publish cum + scount once per batch
    uint32_t* gc = cum + (size_t)b * (NBINS + 1);
#pragma unroll
    for (int q = 0; q < 8; ++q) gc[8 * t + q] = c[q];
    if (t == K23T - 1) gc[NBINS] = incl;
#pragma unroll
    for (int q = 0; q < 8; ++q)
      if (c[q] < NPTS && c[q + 1] >= NPTS) {
        uint32_t sc = c[q + 1];
        scount[b] = (sc > SCAP) ? SCAP : sc;
      }
    if (t == K23T - 1 && incl < NPTS) scount[b] = incl;   // defensive
  }
  __syncthreads();

  // ---- scatter this segment's candidates via LDS cum ----
  uint32_t M = cand_cnt[(b * NSEG + s) * CNTSTRIDE];
  if (M > SEGCAP) M = SEGCAP;
  const uint64_t* cb = cand + ((size_t)b * NSEG + s) * SEGCAP;
  for (int jj = t; jj < SEGCAP; jj += K23T) {
    if ((uint32_t)jj < M) {
      uint64_t key = cb[jj];
      float u = __uint_as_float((uint32_t)(key >> 32));
      int bin = (int)(u * 65536.0f);
      uint32_t c0 = lcum[bin];
      if (c0 < NPTS) {                       // bin fully past rank 16384?
        uint32_t pos = atomicAdd(&fill[(size_t)b * NBINS + bin], 1u);
        uint32_t sl = c0 + pos;
        if (sl < SCAP) sorted[(size_t)b * SCAP + sl] = key;
      }
    }
  }
}

// K4: thread-per-slot exact rank (count smaller keys in own bin), gather
// p[idx], emit. Keys unique -> exact stable order, bit-identical to argsort.
__global__ __launch_bounds__(256) void k_rank(
    const float* __restrict__ p, const uint64_t* __restrict__ sorted,
    const uint32_t* __restrict__ cum, const uint32_t* __restrict__ scount,
    float* __restrict__ out) {
  const int b = blockIdx.y;
  const uint32_t j = blockIdx.x * 256 + threadIdx.x;
  if (j >= scount[b]) return;
  const uint64_t* sb = sorted + (size_t)b * SCAP;
  uint64_t key = sb[j];
  float u = __uint_as_float((uint32_t)(key >> 32));
  int bin = (int)(u * 65536.0f);
  const uint32_t* gc = cum + (size_t)b * (NBINS + 1);
  uint32_t c0 = gc[bin], c1 = gc[bin + 1];
  uint32_t r = c0;
  for (uint32_t l = c0; l < c1; ++l) r += (sb[l] < key) ? 1u : 0u;
  if (r < NPTS) {
    uint32_t idx = (uint32_t)key;
    const float* pp = p + (size_t)b * NN * 3 + 3 * (size_t)idx;
    float* o = out + ((size_t)b * NPTS + r) * 3;
    o[0] = pp[0]; o[1] = pp[1]; o[2] = pp[2];
  }
}

extern "C" void kernel_launch(void* const* d_in, const int* in_sizes, int n_in,
                              void* d_out, int out_size, void* d_ws, size_t ws_size,
                              hipStream_t stream) {
  const float* p = (const float*)d_in[0];
  float* out = (float*)d_out;
  uint8_t* ws = (uint8_t*)d_ws;

  size_t off_cand   = 0;                                            // 8 MB
  size_t off_sorted = off_cand + (size_t)NB * NSEG * SEGCAP * 8;    // +5.24 MB
  size_t off_cum    = off_sorted + (size_t)NB * SCAP * 8;           // +0.52 MB
  size_t off_scnt   = off_cum + (size_t)NB * (NBINS + 1) * 4;       // +128 B
  size_t off_zero   = off_scnt + 128;                               // zeroed:
  size_t off_cnt    = off_zero;                                     //  cnt 32 KB
  size_t off_hist   = off_cnt + (size_t)NB * NSEG * CNTSTRIDE * 4;  //  hist 512 KB
  size_t off_fill   = off_hist + (size_t)NB * NBINS * 4;            //  fill 512 KB
  size_t zero_bytes = off_fill + (size_t)NB * NBINS * 4 - off_zero;

  uint64_t* cand     = (uint64_t*)(ws + off_cand);
  uint64_t* sorted   = (uint64_t*)(ws + off_sorted);
  uint32_t* cum      = (uint32_t*)(ws + off_cum);
  uint32_t* scount   = (uint32_t*)(ws + off_scnt);
  uint32_t* cand_cnt = (uint32_t*)(ws + off_cnt);
  uint32_t* hist     = (uint32_t*)(ws + off_hist);
  uint32_t* fill     = (uint32_t*)(ws + off_fill);

  // Host-side threefry key derivation (partitionable mode, verified absmax=0):
  // key(42) -> split(32) via cipher(key,(0,b)) -> split(2)[0] via cipher(kb,(0,0)).
  Keys keys;
  for (int b = 0; b < NB; ++b) {
    uint32_t kb0, kb1, kp0, kp1;
    tf2x32(0u, 42u, 0u, (uint32_t)b, &kb0, &kb1);
    tf2x32(kb0, kb1, 0u, 0u, &kp0, &kp1);
    keys.k[2 * b] = kp0; keys.k[2 * b + 1] = kp1;
  }

  hipMemsetAsync(ws + off_zero, 0, zero_bytes, stream);
  dim3 g1(NN / 1024, NB);          // 4 points per thread
  k_candidates<<<g1, 256, 0, stream>>>(p, keys, cand, cand_cnt, hist);
  dim3 g23(NSEG, NB);              // block = (segment, batch)
  k_scan_scatter<<<g23, K23T, 0, stream>>>(hist, cand, cand_cnt, cum,
                                           scount, fill, sorted);
  dim3 g4(SCAP / 256, NB);
  k_rank<<<g4, 256, 0, stream>>>(p, sorted, cum, scount, out);
}

// Round 3
// 308.480 us; speedup vs baseline: 3.4794x; 1.0609x over previous
//
#include <hip/hip_runtime.h>
#include <stdint.h>

#define NB 32
#define NN 524288
#define NPTS 16384
#define NSEG 8             // padded sub-counters per batch for K1 block appends
#define SEGCAP 4096        // slots per segment (E=2196, sd~47 at tight THRESH)
#define SCAP 20480         // scatter buffer per batch (>= 16384 + max bin ~30)
#define NBINS 4096
#define THRESH 0.0478515625f   // 3136/65536 exact; u_(16384)~0.0448, 9-sigma
#define CNTSTRIDE 32       // uint32s per counter -> 128B line padding

struct Keys { uint32_t k[2 * NB]; };

__host__ __device__ static inline void tf2x32(uint32_t k0, uint32_t k1,
                                              uint32_t x0, uint32_t x1,
                                              uint32_t* o0, uint32_t* o1) {
  uint32_t ks2 = k0 ^ k1 ^ 0x1BD11BDAu;
  x0 += k0; x1 += k1;
#define TFR(r) { x0 += x1; x1 = (x1 << (r)) | (x1 >> (32 - (r))); x1 ^= x0; }
  TFR(13) TFR(15) TFR(26) TFR(6)
  x0 += k1; x1 += ks2 + 1u;
  TFR(17) TFR(29) TFR(16) TFR(24)
  x0 += ks2; x1 += k0 + 2u;
  TFR(13) TFR(15) TFR(26) TFR(6)
  x0 += k0; x1 += k1 + 3u;
  TFR(17) TFR(29) TFR(16) TFR(24)
  x0 += k1; x1 += ks2 + 4u;
  TFR(13) TFR(15) TFR(26) TFR(6)
  x0 += ks2; x1 += k0 + 5u;
#undef TFR
  *o0 = x0; *o1 = x1;
}

// K1: threefry FIRST, load point ONLY if u < THRESH (4.8% of points).
// u depends only on the index, so the 201 MB stream becomes a ~50 MB
// sparse line fetch; no histogram work here (moved to K23's LDS).
__global__ __launch_bounds__(256) void k_candidates(
    const float* __restrict__ p, Keys keys,
    uint64_t* __restrict__ cand, uint32_t* __restrict__ cand_cnt) {
  const int b = blockIdx.y;
  const int t = threadIdx.x;
  const int i0 = (blockIdx.x * 256 + t) * 4;            // first of 4 points
  const uint32_t kp0 = keys.k[2 * b], kp1 = keys.k[2 * b + 1];
  const float* pb = p + (size_t)b * NN * 3;

  uint64_t mykeys[4];
  int nc = 0;
#pragma unroll
  for (int j = 0; j < 4; ++j) {
    uint32_t o0, o1;
    tf2x32(kp0, kp1, 0u, (uint32_t)(i0 + j), &o0, &o1);
    uint32_t bits = o0 ^ o1;
    float u = __uint_as_float((bits >> 9) | 0x3F800000u) - 1.0f;
    if (u < THRESH) {
      const float* pp = pb + 3 * (size_t)(i0 + j);
      float x = pp[0], y = pp[1], z = pp[2];
      if (((x + y) + z) != 0.0f)       // keep reference's reduce order
        mykeys[nc++] = ((uint64_t)__float_as_uint(u) << 32) | (uint32_t)(i0 + j);
    }
  }

  __shared__ uint32_t lcnt, lbase;
  if (t == 0) lcnt = 0u;
  __syncthreads();
  uint32_t loc = 0u;
  if (nc) loc = atomicAdd(&lcnt, (uint32_t)nc);
  __syncthreads();
  const int seg = blockIdx.x & (NSEG - 1);
  if (t == 0)
    lbase = atomicAdd(&cand_cnt[(b * NSEG + seg) * CNTSTRIDE], lcnt);
  __syncthreads();
  uint64_t* cb = cand + ((size_t)b * NSEG + seg) * SEGCAP;
  for (int j = 0; j < nc; ++j) {
    uint32_t slot = lbase + loc + j;
    if (slot < SEGCAP) cb[slot] = mykeys[j];
  }
}

// K23: one 1024-thread block per batch. LDS histogram from candidate keys
// (~17.5K per batch), LDS scan of 4096 bins, LDS-fill scatter into global
// bin-contiguous slots. Publishes cum + scount for K4. No global hist/fill
// buffers, no 512 KB memsets, no random-bin global atomics anywhere.
__global__ __launch_bounds__(1024) void k_scan_scatter(
    const uint64_t* __restrict__ cand, const uint32_t* __restrict__ cand_cnt,
    uint32_t* __restrict__ cum, uint32_t* __restrict__ scount,
    uint64_t* __restrict__ sorted) {
  const int b = blockIdx.x;
  const int t = threadIdx.x;
  const int lane = t & 63, wave = t >> 6;
  __shared__ uint32_t lhist[NBINS];          // phase 2: reused as fill
  __shared__ uint32_t lcum[NBINS + 1];
  __shared__ uint32_t wsum[16];
  __shared__ uint32_t segM[NSEG];

  for (int i = t; i < NBINS; i += 1024) lhist[i] = 0u;
  if (t < NSEG) {
    uint32_t M = cand_cnt[(b * NSEG + t) * CNTSTRIDE];
    segM[t] = (M > SEGCAP) ? SEGCAP : M;
  }
  __syncthreads();

  // ---- LDS histogram over all segments' candidates ----
#pragma unroll
  for (int s = 0; s < NSEG; ++s) {
    const uint32_t M = segM[s];
    const uint64_t* cb = cand + ((size_t)b * NSEG + s) * SEGCAP;
    for (uint32_t j = t; j < M; j += 1024) {
      uint32_t ub = (uint32_t)(cb[j] >> 32);
      int bin = (int)(__uint_as_float(ub) * 65536.0f);
      atomicAdd(&lhist[bin], 1u);
    }
  }
  __syncthreads();

  // ---- exclusive scan of 4096 bins (4 per thread, 2-level wave scan) ----
  uint32_t h0 = lhist[4 * t], h1 = lhist[4 * t + 1],
           h2 = lhist[4 * t + 2], h3 = lhist[4 * t + 3];
  uint32_t s4 = h0 + h1 + h2 + h3;
  uint32_t v = s4;
  for (int off = 1; off < 64; off <<= 1) {
    uint32_t n = __shfl_up(v, off, 64);
    if (lane >= off) v += n;
  }
  if (lane == 63) wsum[wave] = v;
  __syncthreads();
  if (t < 16) {
    uint32_t w = wsum[t];
    for (int off = 1; off < 16; off <<= 1) {
      uint32_t n = __shfl_up(w, off, 64);
      if (t >= off) w += n;
    }
    wsum[t] = w;
  }
  __syncthreads();
  uint32_t incl = v + (wave ? wsum[wave - 1] : 0u);
  uint32_t c[5];
  c[0] = incl - s4; c[1] = c[0] + h0; c[2] = c[1] + h1;
  c[3] = c[2] + h2; c[4] = incl;
  lcum[4 * t] = c[0]; lcum[4 * t + 1] = c[1];
  lcum[4 * t + 2] = c[2]; lcum[4 * t + 3] = c[3];
  if (t == 1023) lcum[NBINS] = incl;
  uint32_t* gc = cum + (size_t)b * (NBINS + 1);
  gc[4 * t] = c[0]; gc[4 * t + 1] = c[1];
  gc[4 * t + 2] = c[2]; gc[4 * t + 3] = c[3];
  if (t == 1023) gc[NBINS] = incl;
#pragma unroll
  for (int q = 0; q < 4; ++q)
    if (c[q] < NPTS && c[q + 1] >= NPTS) {
      uint32_t sc = c[q + 1];
      scount[b] = (sc > SCAP) ? SCAP : sc;
    }
  if (t == 1023 && incl < NPTS) scount[b] = incl;   // defensive
  __syncthreads();                                   // lhist reads all done

  // ---- reuse lhist as fill, scatter via LDS cum ----
  for (int i = t; i < NBINS; i += 1024) lhist[i] = 0u;
  __syncthreads();
#pragma unroll
  for (int s = 0; s < NSEG; ++s) {
    const uint32_t M = segM[s];
    const uint64_t* cb = cand + ((size_t)b * NSEG + s) * SEGCAP;
    for (uint32_t j = t; j < M; j += 1024) {
      uint64_t key = cb[j];
      int bin = (int)(__uint_as_float((uint32_t)(key >> 32)) * 65536.0f);
      uint32_t c0 = lcum[bin];
      if (c0 < NPTS) {                       // bin fully past rank 16384?
        uint32_t pos = atomicAdd(&lhist[bin], 1u);
        uint32_t sl = c0 + pos;
        if (sl < SCAP) sorted[(size_t)b * SCAP + sl] = key;
      }
    }
  }
}

// K4: thread-per-slot exact rank (count smaller keys in own bin), gather
// p[idx], emit. Keys unique -> exact stable order, bit-identical to argsort.
__global__ __launch_bounds__(256) void k_rank(
    const float* __restrict__ p, const uint64_t* __restrict__ sorted,
    const uint32_t* __restrict__ cum, const uint32_t* __restrict__ scount,
    float* __restrict__ out) {
  const int b = blockIdx.y;
  const uint32_t j = blockIdx.x * 256 + threadIdx.x;
  if (j >= scount[b]) return;
  const uint64_t* sb = sorted + (size_t)b * SCAP;
  uint64_t key = sb[j];
  float u = __uint_as_float((uint32_t)(key >> 32));
  int bin = (int)(u * 65536.0f);
  const uint32_t* gc = cum + (size_t)b * (NBINS + 1);
  uint32_t c0 = gc[bin], c1 = gc[bin + 1];
  uint32_t r = c0;
  for (uint32_t l = c0; l < c1; ++l) r += (sb[l] < key) ? 1u : 0u;
  if (r < NPTS) {
    uint32_t idx = (uint32_t)key;
    const float* pp = p + (size_t)b * NN * 3 + 3 * (size_t)idx;
    float* o = out + ((size_t)b * NPTS + r) * 3;
    o[0] = pp[0]; o[1] = pp[1]; o[2] = pp[2];
  }
}

extern "C" void kernel_launch(void* const* d_in, const int* in_sizes, int n_in,
                              void* d_out, int out_size, void* d_ws, size_t ws_size,
                              hipStream_t stream) {
  const float* p = (const float*)d_in[0];
  float* out = (float*)d_out;
  uint8_t* ws = (uint8_t*)d_ws;

  size_t off_cand   = 0;                                            // 8 MB
  size_t off_sorted = off_cand + (size_t)NB * NSEG * SEGCAP * 8;    // +5.24 MB
  size_t off_cum    = off_sorted + (size_t)NB * SCAP * 8;           // +0.52 MB
  size_t off_scnt   = off_cum + (size_t)NB * (NBINS + 1) * 4;       // +128 B
  size_t off_cnt    = off_scnt + 128;                               // zeroed 32 KB
  size_t zero_bytes = (size_t)NB * NSEG * CNTSTRIDE * 4;

  uint64_t* cand     = (uint64_t*)(ws + off_cand);
  uint64_t* sorted   = (uint64_t*)(ws + off_sorted);
  uint32_t* cum      = (uint32_t*)(ws + off_cum);
  uint32_t* scount   = (uint32_t*)(ws + off_scnt);
  uint32_t* cand_cnt = (uint32_t*)(ws + off_cnt);

  // Host-side threefry key derivation (partitionable mode, verified absmax=0):
  // key(42) -> split(32) via cipher(key,(0,b)) -> split(2)[0] via cipher(kb,(0,0)).
  Keys keys;
  for (int b = 0; b < NB; ++b) {
    uint32_t kb0, kb1, kp0, kp1;
    tf2x32(0u, 42u, 0u, (uint32_t)b, &kb0, &kb1);
    tf2x32(kb0, kb1, 0u, 0u, &kp0, &kp1);
    keys.k[2 * b] = kp0; keys.k[2 * b + 1] = kp1;
  }

  hipMemsetAsync(ws + off_cnt, 0, zero_bytes, stream);   // 32 KB only
  dim3 g1(NN / 1024, NB);          // 4 points per thread
  k_candidates<<<g1, 256, 0, stream>>>(p, keys, cand, cand_cnt);
  k_scan_scatter<<<NB, 1024, 0, stream>>>(cand, cand_cnt, cum, scount, sorted);
  dim3 g4(SCAP / 256, NB);
  k_rank<<<g4, 256, 0, stream>>>(p, sorted, cum, scount, out);
}